// Round 19
// baseline (165.564 us; speedup 1.0000x reference)
//
#include <hip/hip_runtime.h>

typedef __attribute__((ext_vector_type(8))) short short8;
typedef __attribute__((ext_vector_type(8), aligned(8))) short short8u;  // 8B-aligned 16B load
typedef __attribute__((ext_vector_type(4))) short short4v;
typedef __attribute__((ext_vector_type(4))) float f32x4;
typedef unsigned short ushort;
typedef unsigned int uint;

static __device__ __forceinline__ float sgn(float v) {
    return (v > 0.f) ? 1.f : ((v < 0.f) ? -1.f : 0.f);
}
static __device__ __forceinline__ ushort f2bf(float f) {       // RNE (epilogues)
    uint u = __builtin_bit_cast(uint, f);
    u += 0x7fffu + ((u >> 16) & 1u);
    return (ushort)(u >> 16);
}
static __device__ __forceinline__ ushort f2bf_t(float f) {     // truncation (staging)
    return (ushort)(__builtin_bit_cast(uint, f) >> 16);
}
static __device__ __forceinline__ ushort sgn2bf(float v) {
    return (v > 0.f) ? (ushort)0x3F80 : ((v < 0.f) ? (ushort)0xBF80 : (ushort)0);
}

// ------- prep_misc: pad-zero h1p/h2p halos + all conv weight fragments ----------
__global__ void prep_misc(ushort* __restrict__ h1p, ushort* __restrict__ h2p,
                          const float* __restrict__ w2, const float* __restrict__ w3,
                          const float* __restrict__ w1,
                          ushort* __restrict__ f2, ushort* __restrict__ f3,
                          ushort* __restrict__ f1) {
    int t = blockIdx.x * 256 + threadIdx.x;
    const short8 z = {};
    if (t < 115712) {                       // h1p: 128 b x 452 cells x 2 halves
        int b = t / 904, r = t % 904;
        int cell = r >> 1, half = r & 1;
        int y, xx;
        if (cell < 114)      { y = 0;   xx = cell; }
        else if (cell < 228) { y = 113; xx = cell - 114; }
        else { int s = cell - 228; y = 1 + (s >> 1); xx = (s & 1) ? 113 : 0; }
        *(short8*)&h1p[((b * 114 + y) * 114 + xx) * 16 + half * 8] = z;
    } else if (t < 232448) {
        t -= 115712;                        // h2p: 128 b x 228 cells x 4 quarters
        int b = t / 912, r = t % 912;
        int cell = r >> 2, qq = r & 3;
        int y, xx;
        if (cell < 58)       { y = 0;  xx = cell; }
        else if (cell < 116) { y = 57; xx = cell - 58; }
        else { int s = cell - 116; y = 1 + (s >> 1); xx = (s & 1) ? 57 : 0; }
        *(short8*)&h2p[((b * 58 + y) * 58 + xx) * 32 + qq * 8] = z;
    } else {
        int tw = t - 232448;
        if (tw < 5120) {
            int j = tw & 7, l = (tw >> 3) & 63, nc = tw >> 9;  // nc = c*2 + n
            int n = nc & 1, c = nc >> 1;
            int k = c * 32 + ((l >> 4) << 3) + j;
            ushort v = 0;
            if (k < 144) {
                int ky = k / 48, rem = k % 48, kx = rem >> 4, ci = rem & 15;
                int co = n * 16 + (l & 15);
                v = sgn2bf(w2[((co * 16 + ci) * 3 + ky) * 3 + kx]);
            }
            f2[tw] = v;
        } else if (tw < 23552) {
            int t2 = tw - 5120;
            int j = t2 & 7, l = (t2 >> 3) & 63, nc = t2 >> 9;  // nc = c*4 + n
            int n = nc & 3, c = nc >> 2;
            int k = c * 32 + ((l >> 4) << 3) + j;               // < 288
            int ky = k / 96, rem = k % 96, kx = rem >> 5, ci = rem & 31;
            int co = n * 16 + (l & 15);
            f3[t2] = sgn2bf(w3[((co * 32 + ci) * 3 + ky) * 3 + kx]);
        } else if (tw < 24576) {
            int t1 = tw - 23552;
            int j = t1 & 7, l = (t1 >> 3) & 63, c = t1 >> 9;    // c = 0,1
            int k = c * 32 + ((l >> 4) << 3) + j;               // 0..63
            int ky = k >> 4, kx = (k >> 2) & 3, ci = k & 3;
            ushort v = 0;
            if (ky < 3 && kx < 3 && ci < 3) {
                int co = l & 15;
                v = sgn2bf(w1[((co * 3 + ci) * 3 + ky) * 3 + kx]);
            }
            f1[t1] = v;
        }
    }
}

// ---------------- wf1_prep_t: wf1 fp32 [128][50176] -> sign bf16, K-permuted ----
__global__ void wf1_prep_t(const float* __restrict__ wf1, ushort* __restrict__ wsg) {
    const int pt  = blockIdx.x;      // 0..6
    const int co2 = blockIdx.y;      // 0..127
    __shared__ ushort T[64][114];
#pragma unroll
    for (int k = 0; k < 7; ++k) {
        int i = threadIdx.x + k * 256;      // 0..1791 over [64 co][28 p-float4]
        int co = i / 28, pf = i % 28;
        const float4 v = *(const float4*)&wf1[(size_t)co2 * 50176 + co * 784 + pt * 112 + pf * 4];
        T[co][pf * 4 + 0] = sgn2bf(v.x);
        T[co][pf * 4 + 1] = sgn2bf(v.y);
        T[co][pf * 4 + 2] = sgn2bf(v.z);
        T[co][pf * 4 + 3] = sgn2bf(v.w);
    }
    __syncthreads();
#pragma unroll
    for (int k = 0; k < 7; ++k) {
        int j = threadIdx.x + k * 256;      // 0..1791 over [112 p][16 co-groups]
        int p = j >> 4, cg = j & 15;
        ushort pk[4] = {T[cg * 4 + 0][p], T[cg * 4 + 1][p], T[cg * 4 + 2][p], T[cg * 4 + 3][p]};
        *(short4v*)&wsg[(size_t)co2 * 50176 + (size_t)(pt * 112 + p) * 64 + cg * 4] =
            *(const short4v*)pk;
    }
}

// ---------------- conv1: FUSED x-prep + MFMA, 8 waves / 2 pooled rows (r17) -----
__global__ __launch_bounds__(512) void
conv1_fused(const float* __restrict__ x,     // [128,3,224,224] fp32
            const ushort* __restrict__ wfrag,// [2][64][8] bf16
            const float* __restrict__ bias,  // [16]
            ushort* __restrict__ h1p) {      // [128,114,114,16] bf16
    const int py2 = blockIdx.x;              // pooled row pair 0..55
    const int b   = blockIdx.z;
    const int wv = threadIdx.x >> 6, l = threadIdx.x & 63;

    __shared__ ushort lx[6][232][4];         // 6 input rows, stride-232 cols, 4ch bf16

    if (wv < 6) {
        const int row = 4 * py2 - 1 + wv;
        const bool rok = ((unsigned)row < 224u);
        const float* xb = x + (((size_t)b * 3) * 224 + (rok ? row : 0)) * 224;
#pragma unroll
        for (int it = 0; it < 2; ++it) {
            const int cp = l + it * 64;          // col-pair id 0..111
            if (cp < 112) {
                float2 v0 = {0.f, 0.f}, v1 = {0.f, 0.f}, v2 = {0.f, 0.f};
                if (rok) {
                    v0 = *(const float2*)(xb + 2 * cp);
                    v1 = *(const float2*)(xb + 50176 + 2 * cp);
                    v2 = *(const float2*)(xb + 100352 + 2 * cp);
                }
                ushort pk0[4] = {f2bf_t(v0.x), f2bf_t(v1.x), f2bf_t(v2.x), 0};
                ushort pk1[4] = {f2bf_t(v0.y), f2bf_t(v1.y), f2bf_t(v2.y), 0};
                *(short4v*)&lx[wv][1 + 2 * cp][0] = *(const short4v*)pk0;
                *(short4v*)&lx[wv][2 + 2 * cp][0] = *(const short4v*)pk1;
            }
        }
        if (l == 62) { ushort z[4] = {0,0,0,0}; *(short4v*)&lx[wv][0][0]   = *(const short4v*)z; }
        if (l == 63) { ushort z[4] = {0,0,0,0}; *(short4v*)&lx[wv][225][0] = *(const short4v*)z; }
    }
    __syncthreads();

    const int sr = wv >> 2, ww = wv & 3;     // sub pooled-row 0..1, x-group 0..3
    const int lhi = l >> 4, llo = l & 15;
    const int q = llo >> 2, e = llo & 3;
    const int xl0 = ww * 56 + 2 * q + (e & 1);   // padded col base
    const int r0  = 2 * sr + (e >> 1);           // staged-row base (0..5 window)

    short8 wf[2];
#pragma unroll
    for (int c = 0; c < 2; ++c)
        wf[c] = *(const short8*)&wfrag[(c * 64 + l) * 8];
    const float bv = bias[llo];

    const ushort* lptr[2]; bool vld[2];
#pragma unroll
    for (int c = 0; c < 2; ++c) {
        const int cc = c * 4 + lhi, ky = cc >> 1, half = cc & 1;
        vld[c] = (ky < 3);
        const int kyc = vld[c] ? ky : 0;
        lptr[c] = &lx[r0 + kyc][xl0 + 2 * half][0];
    }

    f32x4 acc[7];
#pragma unroll
    for (int i = 0; i < 7; ++i) acc[i] = (f32x4){0.f, 0.f, 0.f, 0.f};

#pragma unroll
    for (int i = 0; i < 7; ++i)
#pragma unroll
        for (int c = 0; c < 2; ++c) {
            short8 a = {};
            if (vld[c]) a = (short8)(*(const short8u*)(lptr[c] + i * 32));
            acc[i] = __builtin_amdgcn_mfma_f32_16x16x32_bf16(a, wf[c], acc[i], 0, 0, 0);
        }

    const size_t obase = ((size_t)(b * 114 + 1 + 2 * py2 + sr) * 114 + 1) * 16 + llo;
#pragma unroll
    for (int i = 0; i < 7; ++i) {
        float v = fmaxf(fmaxf(acc[i][0], acc[i][1]), fmaxf(acc[i][2], acc[i][3]));
        v = fmaxf(v + bv, 0.f);
        h1p[obase + (size_t)(ww * 28 + i * 4 + lhi) * 16] = f2bf(v);
    }
}

// ---------------- conv2: MFMA im2col, streamed weights, occupancy 4 w/SIMD ------
// Weights streamed per k-step (frees 40 VGPR); a-loads unbatched (r9 proved
// batching neutral). __launch_bounds__(256,4) -> <=128 VGPR, 16 waves/CU.
__global__ __launch_bounds__(256, 4) void
conv2_mfma(const ushort* __restrict__ h1p,   // [128,114,114,16] bf16
           const ushort* __restrict__ wfrag, // [5][2][64][8] bf16
           const float* __restrict__ bias,   // [32]
           ushort* __restrict__ h2p) {       // [128,58,58,32] bf16
    const int b  = blockIdx.z;
    const int wv = threadIdx.x >> 6, l = threadIdx.x & 63;
    const int mh = wv >> 1, r = wv & 1;
    const int py = blockIdx.x * 2 + r;       // pooled row 0..55
    const int lhi = l >> 4, llo = l & 15;
    const int q = llo >> 2, e = llo & 3;
    const int xpre0 = mh * 56 + 2 * q + (e & 1);
    const int ypre  = 2 * py + (e >> 1);

    const float bv0 = bias[llo], bv1 = bias[16 + llo];

    const ushort* ptr[5]; bool vld[5];
#pragma unroll
    for (int c = 0; c < 5; ++c) {
        const int cc = c * 4 + lhi;          // 0..19, valid < 18
        vld[c] = (cc < 18);
        const int dy = vld[c] ? (cc / 6) : 0;
        const int koff = (cc % 6) * 8;
        ptr[c] = &h1p[(((size_t)(b * 114 + ypre + dy)) * 114 + xpre0) * 16 + koff];
    }

    f32x4 acc[7][2];
#pragma unroll
    for (int m = 0; m < 7; ++m)
#pragma unroll
        for (int n = 0; n < 2; ++n) acc[m][n] = (f32x4){0.f, 0.f, 0.f, 0.f};

#pragma unroll
    for (int c = 0; c < 5; ++c) {
        const short8 wf0 = *(const short8*)&wfrag[(((c * 2 + 0) * 64) + l) * 8];
        const short8 wf1 = *(const short8*)&wfrag[(((c * 2 + 1) * 64) + l) * 8];
#pragma unroll
        for (int m = 0; m < 7; ++m) {
            short8 t = {};
            if (vld[c]) t = *(const short8*)(ptr[c] + m * 128);
            acc[m][0] = __builtin_amdgcn_mfma_f32_16x16x32_bf16(t, wf0, acc[m][0], 0, 0, 0);
            acc[m][1] = __builtin_amdgcn_mfma_f32_16x16x32_bf16(t, wf1, acc[m][1], 0, 0, 0);
        }
    }

    const size_t obase = ((size_t)(b * 58 + 1 + py) * 58 + 1) * 32 + llo;
#pragma unroll
    for (int m = 0; m < 7; ++m) {
        const size_t po = obase + (size_t)(mh * 28 + m * 4 + lhi) * 32;
        float v0 = fmaxf(fmaxf(acc[m][0][0], acc[m][0][1]), fmaxf(acc[m][0][2], acc[m][0][3]));
        h2p[po]      = f2bf(fmaxf(v0 + bv0, 0.f));
        float v1 = fmaxf(fmaxf(acc[m][1][0], acc[m][1][1]), fmaxf(acc[m][1][2], acc[m][1][3]));
        h2p[po + 16] = f2bf(fmaxf(v1 + bv1, 0.f));
    }
}

// ---------------- conv3: MFMA im2col, unbatched loads, occupancy 3 w/SIMD -------
// a-loads unbatched (neutral per r9); __launch_bounds__(256,3) -> <=168 VGPR,
// 12 waves/CU (was 8).
__global__ __launch_bounds__(256, 3) void
conv3_mfma(const ushort* __restrict__ h2p,   // [128,58,58,32] bf16
           const ushort* __restrict__ wfrag, // [9][4][64][8] bf16
           const float* __restrict__ bias,   // [64]
           ushort* __restrict__ h3b) {       // [128][50176] bf16 (p*64+co)
    const int b  = blockIdx.z;
    const int wv = threadIdx.x >> 6, l = threadIdx.x & 63;
    const int py = blockIdx.x * 4 + wv;      // pooled row 0..27
    const int lhi = l >> 4, llo = l & 15;
    const int q = llo >> 2, e = llo & 3;
    const int xpre0 = 2 * q + (e & 1);
    const int ypre  = 2 * py + (e >> 1);

    const float bv[4] = {bias[llo], bias[16 + llo], bias[32 + llo], bias[48 + llo]};

    const ushort* ptr[9];
#pragma unroll
    for (int c = 0; c < 9; ++c) {
        const int cc = c * 4 + lhi;          // 0..35, all valid
        const int dy = cc / 12, koff = (cc % 12) * 8;
        ptr[c] = &h2p[(((size_t)(b * 58 + ypre + dy)) * 58 + xpre0) * 32 + koff];
    }

    f32x4 acc[7][4];
#pragma unroll
    for (int m = 0; m < 7; ++m)
#pragma unroll
        for (int n = 0; n < 4; ++n) acc[m][n] = (f32x4){0.f, 0.f, 0.f, 0.f};

#pragma unroll
    for (int c = 0; c < 9; ++c) {
        const short8 wf0 = *(const short8*)&wfrag[(((c * 4 + 0) * 64) + l) * 8];
        const short8 wf1 = *(const short8*)&wfrag[(((c * 4 + 1) * 64) + l) * 8];
        const short8 wf2 = *(const short8*)&wfrag[(((c * 4 + 2) * 64) + l) * 8];
        const short8 wf3 = *(const short8*)&wfrag[(((c * 4 + 3) * 64) + l) * 8];
#pragma unroll
        for (int m = 0; m < 7; ++m) {
            const short8 t = *(const short8*)(ptr[c] + m * 256);
            acc[m][0] = __builtin_amdgcn_mfma_f32_16x16x32_bf16(t, wf0, acc[m][0], 0, 0, 0);
            acc[m][1] = __builtin_amdgcn_mfma_f32_16x16x32_bf16(t, wf1, acc[m][1], 0, 0, 0);
            acc[m][2] = __builtin_amdgcn_mfma_f32_16x16x32_bf16(t, wf2, acc[m][2], 0, 0, 0);
            acc[m][3] = __builtin_amdgcn_mfma_f32_16x16x32_bf16(t, wf3, acc[m][3], 0, 0, 0);
        }
    }

    const size_t obase = (size_t)b * 50176 + (size_t)(py * 28) * 64 + llo;
#pragma unroll
    for (int m = 0; m < 7; ++m) {
        const size_t po = obase + (size_t)(m * 4 + lhi) * 64;
#pragma unroll
        for (int n = 0; n < 4; ++n) {
            float v = fmaxf(fmaxf(acc[m][n][0], acc[m][n][1]),
                            fmaxf(acc[m][n][2], acc[m][n][3]));
            v = fmaxf(v + bv[n], 0.f);
            h3b[po + n * 16] = f2bf(v);
        }
    }
}

// ---------------- FC1 stage A: bf16 MFMA split-K, 32b x 64co per wave (r18) -----
__global__ __launch_bounds__(256) void
fc1_mfmaA(const ushort* __restrict__ actb,  // [128][50176] bf16 (K-permuted)
          const ushort* __restrict__ wsg,   // [128][50176] bf16 (same K-perm)
          float* __restrict__ partials) {   // [49][128][128]
    const int K = 50176;
    const int bt = blockIdx.x * 32, ct = blockIdx.y * 64, ks = blockIdx.z;
    const int wv = threadIdx.x >> 6, l = threadIdx.x & 63;
    const int lhi = l >> 4, llo = l & 15;

    __shared__ float lds[4][32][68];        // 34.8 KB

    f32x4 acc[2][4];
#pragma unroll
    for (int i = 0; i < 2; ++i)
#pragma unroll
        for (int j = 0; j < 4; ++j) acc[i][j] = (f32x4){0.f, 0.f, 0.f, 0.f};

    const int kw = ks * 1024 + wv * 256 + lhi * 8;
    const ushort* a0p = actb + (size_t)(bt + llo)      * K + kw;
    const ushort* a1p = actb + (size_t)(bt + llo + 16) * K + kw;
    const ushort* bp[4];
#pragma unroll
    for (int j = 0; j < 4; ++j)
        bp[j] = wsg + (size_t)(ct + j * 16 + llo) * K + kw;

#pragma unroll
    for (int s = 0; s < 8; ++s) {
        const int off = s * 32;
        const short8 a0 = *(const short8*)(a0p + off);
        const short8 a1 = *(const short8*)(a1p + off);
        short8 bv[4];
#pragma unroll
        for (int j = 0; j < 4; ++j) bv[j] = *(const short8*)(bp[j] + off);
#pragma unroll
        for (int j = 0; j < 4; ++j) {
            acc[0][j] = __builtin_amdgcn_mfma_f32_16x16x32_bf16(a0, bv[j], acc[0][j], 0, 0, 0);
            acc[1][j] = __builtin_amdgcn_mfma_f32_16x16x32_bf16(a1, bv[j], acc[1][j], 0, 0, 0);
        }
    }

    // D: row m = i*16 + lhi*4 + r, col n = j*16 + llo
#pragma unroll
    for (int i = 0; i < 2; ++i)
#pragma unroll
        for (int j = 0; j < 4; ++j)
#pragma unroll
            for (int r = 0; r < 4; ++r)
                lds[wv][i * 16 + lhi * 4 + r][j * 16 + llo] = acc[i][j][r];
    __syncthreads();

    float* pb = partials + (size_t)ks * 16384;
#pragma unroll
    for (int u = 0; u < 8; ++u) {
        int idx = threadIdx.x + u * 256;     // 0..2047
        int m = idx >> 6, n = idx & 63;
        float v = lds[0][m][n] + lds[1][m][n] + lds[2][m][n] + lds[3][m][n];
        pb[(bt + m) * 128 + ct + n] = v;
    }
}

// ---------------- FC1 stage B: reduce 49 partials + bias + relu -----------------
__global__ void fc1_stageB(const float* __restrict__ partials,
                           const float* __restrict__ bf,
                           float* __restrict__ f1) {
    const int o = blockIdx.x * 256 + threadIdx.x;  // 0..16383
    float acc = 0.f;
    for (int ks = 0; ks < 49; ++ks) acc += partials[(size_t)ks * 16384 + o];
    f1[o] = fmaxf(acc + bf[o & 127], 0.f);
}

// ---------------- FC2 ------------------------------------------------------------
__global__ void fc2_kernel(const float* __restrict__ act,
                           const float* __restrict__ wf,
                           const float* __restrict__ bf,
                           float* __restrict__ out) {
    const int o = blockIdx.x * 256 + threadIdx.x;
    if (o >= 128 * 1000) return;
    const int b = o / 1000, co = o % 1000;
    const float* a  = act + b * 128;
    const float* wr = wf + co * 128;
    float acc = 0.f;
#pragma unroll 8
    for (int k = 0; k < 128; ++k)
        acc = fmaf(a[k], sgn(wr[k]), acc);
    out[o] = acc + bf[co];
}

extern "C" void kernel_launch(void* const* d_in, const int* in_sizes, int n_in,
                              void* d_out, int out_size, void* d_ws, size_t ws_size,
                              hipStream_t stream) {
    const float* x   = (const float*)d_in[0];
    const float* w1  = (const float*)d_in[1];
    const float* b1  = (const float*)d_in[2];
    const float* w2  = (const float*)d_in[3];
    const float* b2  = (const float*)d_in[4];
    const float* w3  = (const float*)d_in[5];
    const float* b3  = (const float*)d_in[6];
    const float* wf1 = (const float*)d_in[7];
    const float* bf1 = (const float*)d_in[8];
    const float* wf2 = (const float*)d_in[9];
    const float* bf2 = (const float*)d_in[10];

    // ws layout (peak ~133.1 MB):
    //   h1p bf16 [128,114,114,16] @ 0            (53,231,616)
    //   h3b  bf16 [128][50176]    @ 53,231,616   (12,845,056)  NHWC-permuted K
    //   wsg1 bf16 [128][50176]    @ 66,076,672   (12,845,056)  same K-perm
    //   pa   fp32 [49][16384]     @ 78,921,728   ( 3,211,264)
    //   f1   fp32 [128,128]       @ 82,132,992   (    65,536)
    //   h2p bf16 [128,58,58,32]   @ 105,507,840  (27,557,888)
    //   wf1frag @ 133,065,728 (2,048); wf2frag @ 133,067,776 (10,240);
    //   wf3frag @ 133,078,016 (36,864)
    char* ws = (char*)d_ws;
    ushort* h1p  = (ushort*)ws;
    ushort* h3b  = (ushort*)(ws + 53231616u);
    ushort* wsg1 = (ushort*)(ws + 66076672u);
    float*  pa   = (float*) (ws + 78921728u);
    float*  f1   = (float*) (ws + 82132992u);
    ushort* h2p  = (ushort*)(ws + 105507840u);
    ushort* wf1frag = (ushort*)(ws + 133065728u);
    ushort* wf2frag = (ushort*)(ws + 133067776u);
    ushort* wf3frag = (ushort*)(ws + 133078016u);

    prep_misc<<<1004, 256, 0, stream>>>(h1p, h2p, w2, w3, w1, wf2frag, wf3frag, wf1frag);
    wf1_prep_t<<<dim3(7, 128), 256, 0, stream>>>(wf1, wsg1);
    conv1_fused<<<dim3(56, 1, 128), 512, 0, stream>>>(x, wf1frag, b1, h1p);
    conv2_mfma<<<dim3(28, 1, 128), 256, 0, stream>>>(h1p, wf2frag, b2, h2p);
    conv3_mfma<<<dim3(7, 1, 128), 256, 0, stream>>>(h2p, wf3frag, b3, h3b);
    fc1_mfmaA<<<dim3(4, 2, 49), 256, 0, stream>>>(h3b, wsg1, pa);
    fc1_stageB<<<64, 256, 0, stream>>>(pa, bf1, f1);
    fc2_kernel<<<500, 256, 0, stream>>>(f1, wf2, bf2, (float*)d_out);
}

// Round 20
// 132.697 us; speedup vs baseline: 1.2477x; 1.2477x over previous
//
#include <hip/hip_runtime.h>

typedef __attribute__((ext_vector_type(8))) short short8;
typedef __attribute__((ext_vector_type(8), aligned(8))) short short8u;  // 8B-aligned 16B load
typedef __attribute__((ext_vector_type(4))) short short4v;
typedef __attribute__((ext_vector_type(4))) float f32x4;
typedef unsigned short ushort;
typedef unsigned int uint;

static __device__ __forceinline__ float sgn(float v) {
    return (v > 0.f) ? 1.f : ((v < 0.f) ? -1.f : 0.f);
}
static __device__ __forceinline__ ushort f2bf(float f) {       // RNE (epilogues)
    uint u = __builtin_bit_cast(uint, f);
    u += 0x7fffu + ((u >> 16) & 1u);
    return (ushort)(u >> 16);
}
static __device__ __forceinline__ ushort f2bf_t(float f) {     // truncation (staging)
    return (ushort)(__builtin_bit_cast(uint, f) >> 16);
}
static __device__ __forceinline__ ushort sgn2bf(float v) {
    return (v > 0.f) ? (ushort)0x3F80 : ((v < 0.f) ? (ushort)0xBF80 : (ushort)0);
}

// ------- prep_misc: pad-zero h1p/h2p halos + all conv weight fragments ----------
__global__ void prep_misc(ushort* __restrict__ h1p, ushort* __restrict__ h2p,
                          const float* __restrict__ w2, const float* __restrict__ w3,
                          const float* __restrict__ w1,
                          ushort* __restrict__ f2, ushort* __restrict__ f3,
                          ushort* __restrict__ f1) {
    int t = blockIdx.x * 256 + threadIdx.x;
    const short8 z = {};
    if (t < 115712) {                       // h1p: 128 b x 452 cells x 2 halves
        int b = t / 904, r = t % 904;
        int cell = r >> 1, half = r & 1;
        int y, xx;
        if (cell < 114)      { y = 0;   xx = cell; }
        else if (cell < 228) { y = 113; xx = cell - 114; }
        else { int s = cell - 228; y = 1 + (s >> 1); xx = (s & 1) ? 113 : 0; }
        *(short8*)&h1p[((b * 114 + y) * 114 + xx) * 16 + half * 8] = z;
    } else if (t < 232448) {
        t -= 115712;                        // h2p: 128 b x 228 cells x 4 quarters
        int b = t / 912, r = t % 912;
        int cell = r >> 2, qq = r & 3;
        int y, xx;
        if (cell < 58)       { y = 0;  xx = cell; }
        else if (cell < 116) { y = 57; xx = cell - 58; }
        else { int s = cell - 116; y = 1 + (s >> 1); xx = (s & 1) ? 57 : 0; }
        *(short8*)&h2p[((b * 58 + y) * 58 + xx) * 32 + qq * 8] = z;
    } else {
        int tw = t - 232448;
        if (tw < 5120) {
            int j = tw & 7, l = (tw >> 3) & 63, nc = tw >> 9;  // nc = c*2 + n
            int n = nc & 1, c = nc >> 1;
            int k = c * 32 + ((l >> 4) << 3) + j;
            ushort v = 0;
            if (k < 144) {
                int ky = k / 48, rem = k % 48, kx = rem >> 4, ci = rem & 15;
                int co = n * 16 + (l & 15);
                v = sgn2bf(w2[((co * 16 + ci) * 3 + ky) * 3 + kx]);
            }
            f2[tw] = v;
        } else if (tw < 23552) {
            int t2 = tw - 5120;
            int j = t2 & 7, l = (t2 >> 3) & 63, nc = t2 >> 9;  // nc = c*4 + n
            int n = nc & 3, c = nc >> 2;
            int k = c * 32 + ((l >> 4) << 3) + j;               // < 288
            int ky = k / 96, rem = k % 96, kx = rem >> 5, ci = rem & 31;
            int co = n * 16 + (l & 15);
            f3[t2] = sgn2bf(w3[((co * 32 + ci) * 3 + ky) * 3 + kx]);
        } else if (tw < 24576) {
            int t1 = tw - 23552;
            int j = t1 & 7, l = (t1 >> 3) & 63, c = t1 >> 9;    // c = 0,1
            int k = c * 32 + ((l >> 4) << 3) + j;               // 0..63
            int ky = k >> 4, kx = (k >> 2) & 3, ci = k & 3;
            ushort v = 0;
            if (ky < 3 && kx < 3 && ci < 3) {
                int co = l & 15;
                v = sgn2bf(w1[((co * 3 + ci) * 3 + ky) * 3 + kx]);
            }
            f1[t1] = v;
        }
    }
}

// ---------------- wf1_prep_t: wf1 fp32 [128][50176] -> sign bf16, K-permuted ----
__global__ void wf1_prep_t(const float* __restrict__ wf1, ushort* __restrict__ wsg) {
    const int pt  = blockIdx.x;      // 0..6
    const int co2 = blockIdx.y;      // 0..127
    __shared__ ushort T[64][114];
#pragma unroll
    for (int k = 0; k < 7; ++k) {
        int i = threadIdx.x + k * 256;      // 0..1791 over [64 co][28 p-float4]
        int co = i / 28, pf = i % 28;
        const float4 v = *(const float4*)&wf1[(size_t)co2 * 50176 + co * 784 + pt * 112 + pf * 4];
        T[co][pf * 4 + 0] = sgn2bf(v.x);
        T[co][pf * 4 + 1] = sgn2bf(v.y);
        T[co][pf * 4 + 2] = sgn2bf(v.z);
        T[co][pf * 4 + 3] = sgn2bf(v.w);
    }
    __syncthreads();
#pragma unroll
    for (int k = 0; k < 7; ++k) {
        int j = threadIdx.x + k * 256;      // 0..1791 over [112 p][16 co-groups]
        int p = j >> 4, cg = j & 15;
        ushort pk[4] = {T[cg * 4 + 0][p], T[cg * 4 + 1][p], T[cg * 4 + 2][p], T[cg * 4 + 3][p]};
        *(short4v*)&wsg[(size_t)co2 * 50176 + (size_t)(pt * 112 + p) * 64 + cg * 4] =
            *(const short4v*)pk;
    }
}

// ---------------- conv1: FUSED x-prep + MFMA, 8 waves / 2 pooled rows (r17) -----
__global__ __launch_bounds__(512) void
conv1_fused(const float* __restrict__ x,     // [128,3,224,224] fp32
            const ushort* __restrict__ wfrag,// [2][64][8] bf16
            const float* __restrict__ bias,  // [16]
            ushort* __restrict__ h1p) {      // [128,114,114,16] bf16
    const int py2 = blockIdx.x;              // pooled row pair 0..55
    const int b   = blockIdx.z;
    const int wv = threadIdx.x >> 6, l = threadIdx.x & 63;

    __shared__ ushort lx[6][232][4];         // 6 input rows, stride-232 cols, 4ch bf16

    if (wv < 6) {
        const int row = 4 * py2 - 1 + wv;
        const bool rok = ((unsigned)row < 224u);
        const float* xb = x + (((size_t)b * 3) * 224 + (rok ? row : 0)) * 224;
#pragma unroll
        for (int it = 0; it < 2; ++it) {
            const int cp = l + it * 64;          // col-pair id 0..111
            if (cp < 112) {
                float2 v0 = {0.f, 0.f}, v1 = {0.f, 0.f}, v2 = {0.f, 0.f};
                if (rok) {
                    v0 = *(const float2*)(xb + 2 * cp);
                    v1 = *(const float2*)(xb + 50176 + 2 * cp);
                    v2 = *(const float2*)(xb + 100352 + 2 * cp);
                }
                ushort pk0[4] = {f2bf_t(v0.x), f2bf_t(v1.x), f2bf_t(v2.x), 0};
                ushort pk1[4] = {f2bf_t(v0.y), f2bf_t(v1.y), f2bf_t(v2.y), 0};
                *(short4v*)&lx[wv][1 + 2 * cp][0] = *(const short4v*)pk0;
                *(short4v*)&lx[wv][2 + 2 * cp][0] = *(const short4v*)pk1;
            }
        }
        if (l == 62) { ushort z[4] = {0,0,0,0}; *(short4v*)&lx[wv][0][0]   = *(const short4v*)z; }
        if (l == 63) { ushort z[4] = {0,0,0,0}; *(short4v*)&lx[wv][225][0] = *(const short4v*)z; }
    }
    __syncthreads();

    const int sr = wv >> 2, ww = wv & 3;     // sub pooled-row 0..1, x-group 0..3
    const int lhi = l >> 4, llo = l & 15;
    const int q = llo >> 2, e = llo & 3;
    const int xl0 = ww * 56 + 2 * q + (e & 1);   // padded col base
    const int r0  = 2 * sr + (e >> 1);           // staged-row base (0..5 window)

    short8 wf[2];
#pragma unroll
    for (int c = 0; c < 2; ++c)
        wf[c] = *(const short8*)&wfrag[(c * 64 + l) * 8];
    const float bv = bias[llo];

    const ushort* lptr[2]; bool vld[2];
#pragma unroll
    for (int c = 0; c < 2; ++c) {
        const int cc = c * 4 + lhi, ky = cc >> 1, half = cc & 1;
        vld[c] = (ky < 3);
        const int kyc = vld[c] ? ky : 0;
        lptr[c] = &lx[r0 + kyc][xl0 + 2 * half][0];
    }

    f32x4 acc[7];
#pragma unroll
    for (int i = 0; i < 7; ++i) acc[i] = (f32x4){0.f, 0.f, 0.f, 0.f};

#pragma unroll
    for (int i = 0; i < 7; ++i)
#pragma unroll
        for (int c = 0; c < 2; ++c) {
            short8 a = {};
            if (vld[c]) a = (short8)(*(const short8u*)(lptr[c] + i * 32));
            acc[i] = __builtin_amdgcn_mfma_f32_16x16x32_bf16(a, wf[c], acc[i], 0, 0, 0);
        }

    const size_t obase = ((size_t)(b * 114 + 1 + 2 * py2 + sr) * 114 + 1) * 16 + llo;
#pragma unroll
    for (int i = 0; i < 7; ++i) {
        float v = fmaxf(fmaxf(acc[i][0], acc[i][1]), fmaxf(acc[i][2], acc[i][3]));
        v = fmaxf(v + bv, 0.f);
        h1p[obase + (size_t)(ww * 28 + i * 4 + lhi) * 16] = f2bf(v);
    }
}

// ---------------- conv2: MFMA im2col, wave owns ALL 32 co (2 co-tiles, r18) -----
__global__ __launch_bounds__(256, 2) void
conv2_mfma(const ushort* __restrict__ h1p,   // [128,114,114,16] bf16
           const ushort* __restrict__ wfrag, // [5][2][64][8] bf16
           const float* __restrict__ bias,   // [32]
           ushort* __restrict__ h2p) {       // [128,58,58,32] bf16
    const int b  = blockIdx.z;
    const int wv = threadIdx.x >> 6, l = threadIdx.x & 63;
    const int mh = wv >> 1, r = wv & 1;
    const int py = blockIdx.x * 2 + r;       // pooled row 0..55
    const int lhi = l >> 4, llo = l & 15;
    const int q = llo >> 2, e = llo & 3;
    const int xpre0 = mh * 56 + 2 * q + (e & 1);
    const int ypre  = 2 * py + (e >> 1);

    short8 wf[5][2];
#pragma unroll
    for (int c = 0; c < 5; ++c)
#pragma unroll
        for (int n = 0; n < 2; ++n)
            wf[c][n] = *(const short8*)&wfrag[(((c * 2 + n) * 64) + l) * 8];
    const float bv0 = bias[llo], bv1 = bias[16 + llo];

    const ushort* ptr[5]; bool vld[5];
#pragma unroll
    for (int c = 0; c < 5; ++c) {
        const int cc = c * 4 + lhi;          // 0..19, valid < 18
        vld[c] = (cc < 18);
        const int dy = vld[c] ? (cc / 6) : 0;
        const int koff = (cc % 6) * 8;
        ptr[c] = &h1p[(((size_t)(b * 114 + ypre + dy)) * 114 + xpre0) * 16 + koff];
    }

    f32x4 acc[7][2];
#pragma unroll
    for (int m = 0; m < 7; ++m)
#pragma unroll
        for (int n = 0; n < 2; ++n) acc[m][n] = (f32x4){0.f, 0.f, 0.f, 0.f};

#pragma unroll
    for (int c = 0; c < 5; ++c) {
        short8 a[7];
#pragma unroll
        for (int m = 0; m < 7; ++m) {
            short8 t = {};
            if (vld[c]) t = *(const short8*)(ptr[c] + m * 128);
            a[m] = t;
        }
#pragma unroll
        for (int m = 0; m < 7; ++m) {
            acc[m][0] = __builtin_amdgcn_mfma_f32_16x16x32_bf16(a[m], wf[c][0], acc[m][0], 0, 0, 0);
            acc[m][1] = __builtin_amdgcn_mfma_f32_16x16x32_bf16(a[m], wf[c][1], acc[m][1], 0, 0, 0);
        }
    }

    const size_t obase = ((size_t)(b * 58 + 1 + py) * 58 + 1) * 32 + llo;
#pragma unroll
    for (int m = 0; m < 7; ++m) {
        const size_t po = obase + (size_t)(mh * 28 + m * 4 + lhi) * 32;
        float v0 = fmaxf(fmaxf(acc[m][0][0], acc[m][0][1]), fmaxf(acc[m][0][2], acc[m][0][3]));
        h2p[po]      = f2bf(fmaxf(v0 + bv0, 0.f));
        float v1 = fmaxf(fmaxf(acc[m][1][0], acc[m][1][1]), fmaxf(acc[m][1][2], acc[m][1][3]));
        h2p[po + 16] = f2bf(fmaxf(v1 + bv1, 0.f));
    }
}

// ---------------- conv3: MFMA im2col, wave owns ALL 64 co (4 co-tiles, r18) -----
__global__ __launch_bounds__(256, 2) void
conv3_mfma(const ushort* __restrict__ h2p,   // [128,58,58,32] bf16
           const ushort* __restrict__ wfrag, // [9][4][64][8] bf16
           const float* __restrict__ bias,   // [64]
           ushort* __restrict__ h3b) {       // [128][50176] bf16 (p*64+co)
    const int b  = blockIdx.z;
    const int wv = threadIdx.x >> 6, l = threadIdx.x & 63;
    const int py = blockIdx.x * 4 + wv;      // pooled row 0..27
    const int lhi = l >> 4, llo = l & 15;
    const int q = llo >> 2, e = llo & 3;
    const int xpre0 = 2 * q + (e & 1);
    const int ypre  = 2 * py + (e >> 1);

    const float bv[4] = {bias[llo], bias[16 + llo], bias[32 + llo], bias[48 + llo]};

    const ushort* ptr[9];
#pragma unroll
    for (int c = 0; c < 9; ++c) {
        const int cc = c * 4 + lhi;          // 0..35, all valid
        const int dy = cc / 12, koff = (cc % 12) * 8;
        ptr[c] = &h2p[(((size_t)(b * 58 + ypre + dy)) * 58 + xpre0) * 32 + koff];
    }

    f32x4 acc[7][4];
#pragma unroll
    for (int m = 0; m < 7; ++m)
#pragma unroll
        for (int n = 0; n < 4; ++n) acc[m][n] = (f32x4){0.f, 0.f, 0.f, 0.f};

#pragma unroll
    for (int c = 0; c < 9; ++c) {
        const short8 wf0 = *(const short8*)&wfrag[(((c * 4 + 0) * 64) + l) * 8];
        const short8 wf1 = *(const short8*)&wfrag[(((c * 4 + 1) * 64) + l) * 8];
        const short8 wf2 = *(const short8*)&wfrag[(((c * 4 + 2) * 64) + l) * 8];
        const short8 wf3 = *(const short8*)&wfrag[(((c * 4 + 3) * 64) + l) * 8];
        short8 a[7];
#pragma unroll
        for (int m = 0; m < 7; ++m)
            a[m] = *(const short8*)(ptr[c] + m * 256);
#pragma unroll
        for (int m = 0; m < 7; ++m) {
            acc[m][0] = __builtin_amdgcn_mfma_f32_16x16x32_bf16(a[m], wf0, acc[m][0], 0, 0, 0);
            acc[m][1] = __builtin_amdgcn_mfma_f32_16x16x32_bf16(a[m], wf1, acc[m][1], 0, 0, 0);
            acc[m][2] = __builtin_amdgcn_mfma_f32_16x16x32_bf16(a[m], wf2, acc[m][2], 0, 0, 0);
            acc[m][3] = __builtin_amdgcn_mfma_f32_16x16x32_bf16(a[m], wf3, acc[m][3], 0, 0, 0);
        }
    }

    const size_t obase = (size_t)b * 50176 + (size_t)(py * 28) * 64 + llo;
#pragma unroll
    for (int m = 0; m < 7; ++m) {
        const size_t po = obase + (size_t)(m * 4 + lhi) * 64;
#pragma unroll
        for (int n = 0; n < 4; ++n) {
            float v = fmaxf(fmaxf(acc[m][n][0], acc[m][n][1]),
                            fmaxf(acc[m][n][2], acc[m][n][3]));
            v = fmaxf(v + bv[n], 0.f);
            h3b[po + n * 16] = f2bf(v);
        }
    }
}

// ---------------- FC1 stage A: bf16 MFMA split-K, 32b x 64co per wave (r18) -----
__global__ __launch_bounds__(256) void
fc1_mfmaA(const ushort* __restrict__ actb,  // [128][50176] bf16 (K-permuted)
          const ushort* __restrict__ wsg,   // [128][50176] bf16 (same K-perm)
          float* __restrict__ partials) {   // [49][128][128]
    const int K = 50176;
    const int bt = blockIdx.x * 32, ct = blockIdx.y * 64, ks = blockIdx.z;
    const int wv = threadIdx.x >> 6, l = threadIdx.x & 63;
    const int lhi = l >> 4, llo = l & 15;

    __shared__ float lds[4][32][68];        // 34.8 KB

    f32x4 acc[2][4];
#pragma unroll
    for (int i = 0; i < 2; ++i)
#pragma unroll
        for (int j = 0; j < 4; ++j) acc[i][j] = (f32x4){0.f, 0.f, 0.f, 0.f};

    const int kw = ks * 1024 + wv * 256 + lhi * 8;
    const ushort* a0p = actb + (size_t)(bt + llo)      * K + kw;
    const ushort* a1p = actb + (size_t)(bt + llo + 16) * K + kw;
    const ushort* bp[4];
#pragma unroll
    for (int j = 0; j < 4; ++j)
        bp[j] = wsg + (size_t)(ct + j * 16 + llo) * K + kw;

#pragma unroll
    for (int s = 0; s < 8; ++s) {
        const int off = s * 32;
        const short8 a0 = *(const short8*)(a0p + off);
        const short8 a1 = *(const short8*)(a1p + off);
        short8 bv[4];
#pragma unroll
        for (int j = 0; j < 4; ++j) bv[j] = *(const short8*)(bp[j] + off);
#pragma unroll
        for (int j = 0; j < 4; ++j) {
            acc[0][j] = __builtin_amdgcn_mfma_f32_16x16x32_bf16(a0, bv[j], acc[0][j], 0, 0, 0);
            acc[1][j] = __builtin_amdgcn_mfma_f32_16x16x32_bf16(a1, bv[j], acc[1][j], 0, 0, 0);
        }
    }

    // D: row m = i*16 + lhi*4 + r, col n = j*16 + llo
#pragma unroll
    for (int i = 0; i < 2; ++i)
#pragma unroll
        for (int j = 0; j < 4; ++j)
#pragma unroll
            for (int r = 0; r < 4; ++r)
                lds[wv][i * 16 + lhi * 4 + r][j * 16 + llo] = acc[i][j][r];
    __syncthreads();

    float* pb = partials + (size_t)ks * 16384;
#pragma unroll
    for (int u = 0; u < 8; ++u) {
        int idx = threadIdx.x + u * 256;     // 0..2047
        int m = idx >> 6, n = idx & 63;
        float v = lds[0][m][n] + lds[1][m][n] + lds[2][m][n] + lds[3][m][n];
        pb[(bt + m) * 128 + ct + n] = v;
    }
}

// ---------------- FC1 stage B: reduce 49 partials + bias + relu -----------------
__global__ void fc1_stageB(const float* __restrict__ partials,
                           const float* __restrict__ bf,
                           float* __restrict__ f1) {
    const int o = blockIdx.x * 256 + threadIdx.x;  // 0..16383
    float acc = 0.f;
    for (int ks = 0; ks < 49; ++ks) acc += partials[(size_t)ks * 16384 + o];
    f1[o] = fmaxf(acc + bf[o & 127], 0.f);
}

// ---------------- FC2 ------------------------------------------------------------
__global__ void fc2_kernel(const float* __restrict__ act,
                           const float* __restrict__ wf,
                           const float* __restrict__ bf,
                           float* __restrict__ out) {
    const int o = blockIdx.x * 256 + threadIdx.x;
    if (o >= 128 * 1000) return;
    const int b = o / 1000, co = o % 1000;
    const float* a  = act + b * 128;
    const float* wr = wf + co * 128;
    float acc = 0.f;
#pragma unroll 8
    for (int k = 0; k < 128; ++k)
        acc = fmaf(a[k], sgn(wr[k]), acc);
    out[o] = acc + bf[co];
}

extern "C" void kernel_launch(void* const* d_in, const int* in_sizes, int n_in,
                              void* d_out, int out_size, void* d_ws, size_t ws_size,
                              hipStream_t stream) {
    const float* x   = (const float*)d_in[0];
    const float* w1  = (const float*)d_in[1];
    const float* b1  = (const float*)d_in[2];
    const float* w2  = (const float*)d_in[3];
    const float* b2  = (const float*)d_in[4];
    const float* w3  = (const float*)d_in[5];
    const float* b3  = (const float*)d_in[6];
    const float* wf1 = (const float*)d_in[7];
    const float* bf1 = (const float*)d_in[8];
    const float* wf2 = (const float*)d_in[9];
    const float* bf2 = (const float*)d_in[10];

    // ws layout (peak ~133.1 MB):
    //   h1p bf16 [128,114,114,16] @ 0            (53,231,616)
    //   h3b  bf16 [128][50176]    @ 53,231,616   (12,845,056)  NHWC-permuted K
    //   wsg1 bf16 [128][50176]    @ 66,076,672   (12,845,056)  same K-perm
    //   pa   fp32 [49][16384]     @ 78,921,728   ( 3,211,264)
    //   f1   fp32 [128,128]       @ 82,132,992   (    65,536)
    //   h2p bf16 [128,58,58,32]   @ 105,507,840  (27,557,888)
    //   wf1frag @ 133,065,728 (2,048); wf2frag @ 133,067,776 (10,240);
    //   wf3frag @ 133,078,016 (36,864)
    char* ws = (char*)d_ws;
    ushort* h1p  = (ushort*)ws;
    ushort* h3b  = (ushort*)(ws + 53231616u);
    ushort* wsg1 = (ushort*)(ws + 66076672u);
    float*  pa   = (float*) (ws + 78921728u);
    float*  f1   = (float*) (ws + 82132992u);
    ushort* h2p  = (ushort*)(ws + 105507840u);
    ushort* wf1frag = (ushort*)(ws + 133065728u);
    ushort* wf2frag = (ushort*)(ws + 133067776u);
    ushort* wf3frag = (ushort*)(ws + 133078016u);

    prep_misc<<<1004, 256, 0, stream>>>(h1p, h2p, w2, w3, w1, wf2frag, wf3frag, wf1frag);
    wf1_prep_t<<<dim3(7, 128), 256, 0, stream>>>(wf1, wsg1);
    conv1_fused<<<dim3(56, 1, 128), 512, 0, stream>>>(x, wf1frag, b1, h1p);
    conv2_mfma<<<dim3(28, 1, 128), 256, 0, stream>>>(h1p, wf2frag, b2, h2p);
    conv3_mfma<<<dim3(7, 1, 128), 256, 0, stream>>>(h2p, wf3frag, b3, h3b);
    fc1_mfmaA<<<dim3(4, 2, 49), 256, 0, stream>>>(h3b, wsg1, pa);
    fc1_stageB<<<64, 256, 0, stream>>>(pa, bf1, f1);
    fc2_kernel<<<500, 256, 0, stream>>>(f1, wf2, bf2, (float*)d_out);
}